// Round 8
// baseline (444.986 us; speedup 1.0000x reference)
//
#include <hip/hip_runtime.h>
#include <hip/hip_bf16.h>
#include <stdint.h>

typedef __bf16 bf16;
typedef __attribute__((ext_vector_type(8))) __bf16 bf16x8;
typedef __attribute__((ext_vector_type(4))) float f32x4;

#define NEG_LN10K_32 (-0.28782313662425575f)   // -ln(10000)/32

__device__ __forceinline__ bf16x8 cvt8(f32x4 a, f32x4 b) {
    bf16x8 r;
    r[0] = (bf16)a[0]; r[1] = (bf16)a[1]; r[2] = (bf16)a[2]; r[3] = (bf16)a[3];
    r[4] = (bf16)b[0]; r[5] = (bf16)b[1]; r[6] = (bf16)b[2]; r[7] = (bf16)b[3];
    return r;
}

__device__ __forceinline__ void async_copy16(bf16* lds, const bf16* g) {
    __builtin_amdgcn_global_load_lds((const __attribute__((address_space(1))) void*)g,
                                     (__attribute__((address_space(3))) void*)lds, 16, 0, 0);
}

// ---------------------------------------------------------------------------
// Weight convert fp32->bf16, 6 segments of 1M elems. Grid (512,1,6).
// ---------------------------------------------------------------------------
__global__ __launch_bounds__(256) void wconv6(
    const float* __restrict__ s0, const float* __restrict__ s1, const float* __restrict__ s2,
    const float* __restrict__ s3, const float* __restrict__ s4, const float* __restrict__ s5,
    bf16* __restrict__ d0, bf16* __restrict__ d1, bf16* __restrict__ d2,
    bf16* __restrict__ d3, bf16* __restrict__ d4, bf16* __restrict__ d5)
{
    const int z = blockIdx.z;
    const float* src; bf16* dst;
    switch (z) {
        case 0: src = s0; dst = d0; break;
        case 1: src = s1; dst = d1; break;
        case 2: src = s2; dst = d2; break;
        case 3: src = s3; dst = d3; break;
        case 4: src = s4; dst = d4; break;
        default: src = s5; dst = d5; break;
    }
    const size_t i = ((size_t)blockIdx.x * 256 + threadIdx.x) * 8;
    *(bf16x8*)(dst + i) = cvt8(*(const f32x4*)(src + i), *(const f32x4*)(src + i + 4));
}

// ---------------------------------------------------------------------------
// Tiled transpose fp32->bf16: out[j,i] = in[i,j], 1024x1024. Grid (16,16,2).
// ---------------------------------------------------------------------------
__global__ __launch_bounds__(256) void prepT(
    const float* __restrict__ in0, const float* __restrict__ in1,
    bf16* __restrict__ out0, bf16* __restrict__ out1)
{
    const float* in = blockIdx.z ? in1 : in0;
    bf16* out       = blockIdx.z ? out1 : out0;
    __shared__ float tile[64 * 65];
    const int t  = threadIdx.x;
    const int i0 = blockIdx.y * 64, j0 = blockIdx.x * 64;
    const int r  = t >> 2, cg = (t & 3) * 16;
#pragma unroll
    for (int c = 0; c < 16; c += 4) {
        const f32x4 v = *(const f32x4*)(in + (size_t)(i0 + r) * 1024 + j0 + cg + c);
        tile[r * 65 + cg + c + 0] = v[0];
        tile[r * 65 + cg + c + 1] = v[1];
        tile[r * 65 + cg + c + 2] = v[2];
        tile[r * 65 + cg + c + 3] = v[3];
    }
    __syncthreads();
    bf16x8 o0v, o1v;
#pragma unroll
    for (int ii = 0; ii < 8; ++ii) {
        o0v[ii] = (bf16)tile[(cg + ii) * 65 + r];
        o1v[ii] = (bf16)tile[(cg + 8 + ii) * 65 + r];
    }
    bf16* dst = out + (size_t)(j0 + r) * 1024 + i0 + cg;
    *(bf16x8*)dst       = o0v;
    *(bf16x8*)(dst + 8) = o1v;
}

// ---------------------------------------------------------------------------
// GEMM: C[M,1024](bf16) = A @ W^T (+fp32 residual, +fused RoPE).
// 128x128 tile, 4 waves of 64x64, mfma 16x16x32 bf16, BK=64 via two
// stride-64B sub-buffers (r7: conflict-free, one barrier-pair per 64-K).
//
// Round 8: PIPE variant for the PURE-ASYNC kernels (g1 projections +
// precompute). Those grids are 512/128 blocks = <=2 blocks/CU (GRID-limited),
// so r7's vmcnt(0) drain right after async issue exposes nearly the full
// load latency — and doubling LDS to 64KB for a double-buffer costs them
// ZERO occupancy. PIPE=1: stage(t+1) issued BEFORE compute(t), ONE
// __syncthreads per step (its implied vmcnt(0)/lgkmcnt(0) drain now lands a
// full compute region after issue -> latency hidden, barrier count halved).
// Safe-by-construction: __syncthreads' lgkm semantics mean every wave's
// ds_reads of buf[cur] completed (compiler waits lgkm before MFMA use)
// before any wave passes the barrier and overwrites buf[cur] next step.
// g3 (AF32) keeps the r7 path bit-for-bit as the in-run control (r3 proved
// reg-staged dbuf regresses).
// ---------------------------------------------------------------------------
template<int AF32, int WF32, int PIPE>
__global__ __launch_bounds__(256) void gemm_bt(
    const void* __restrict__ A0v, const void* __restrict__ A1v, const void* __restrict__ A2v,
    const void* __restrict__ W0v, const void* __restrict__ W1v, const void* __restrict__ W2v,
    bf16* __restrict__ C0, bf16* __restrict__ C1, bf16* __restrict__ C2,
    const float* __restrict__ R0, int rope_mask)
{
    const int z = blockIdx.z;
    const void* Av = (z == 0) ? A0v : ((z == 1) ? A1v : A2v);
    const void* Wp = (z == 0) ? W0v : ((z == 1) ? W1v : W2v);
    bf16*       C  = (z == 0) ? C0 : ((z == 1) ? C1 : C2);
    const float* R = (z == 0) ? R0 : nullptr;
    const bool doRope = ((rope_mask >> z) & 1) != 0;

    constexpr int NB = PIPE ? 2 : 1;
    __shared__ __attribute__((aligned(16))) bf16 sA[NB][2][128 * 32];
    __shared__ __attribute__((aligned(16))) bf16 sB[NB][2][128 * 32];

    const int t    = threadIdx.x;
    const int w    = t >> 6;
    const int lane = t & 63;
    const int l16  = lane & 15;
    const int quad = lane >> 4;
    const int wrow = w >> 1;
    const int wcol = w & 1;

    int m0, n0;
    if (gridDim.y == 64) {   // M=8192: XCD stripe swizzle (xcd owns 1024 rows)
        const int fs   = blockIdx.y * 8 + blockIdx.x;
        const int xcd  = fs & 7;
        const int slot = fs >> 3;
        m0 = ((xcd << 3) | (slot >> 3)) * 128;
        n0 = (slot & 7) * 128;
    } else {                 // small (weight-precompute) grids: plain mapping
        m0 = blockIdx.y * 128;
        n0 = blockIdx.x * 128;
    }

    // staging offsets: global source granule pre-swizzled (LDS dest linear)
    const int sgr = ((t & 3) ^ ((t >> 3) & 3)) * 8;
    const size_t aOff = (size_t)(m0 + (t >> 2)) * 1024 + sgr;
    const size_t wOff = (size_t)(n0 + (t >> 2)) * 1024 + sgr;
    // frag-read slot: quad ^ (row>>1)&3  (per-lane constant; r2-proven 0-conflict)
    const int qs = (quad ^ ((l16 >> 1) & 3)) * 8;

    auto stageAasync = [&](int k0, int db) {
        const bf16* g = (const bf16*)Av;
        async_copy16(&sA[db][0][w * 512],        g + aOff + k0);
        async_copy16(&sA[db][0][w * 512 + 2048], g + aOff + 65536 + k0);
        async_copy16(&sA[db][1][w * 512],        g + aOff + k0 + 32);
        async_copy16(&sA[db][1][w * 512 + 2048], g + aOff + 65536 + k0 + 32);
    };
    auto stageBasync = [&](int k0, int db) {
        const bf16* g = (const bf16*)Wp;
        async_copy16(&sB[db][0][w * 512],        g + wOff + k0);
        async_copy16(&sB[db][0][w * 512 + 2048], g + wOff + 65536 + k0);
        async_copy16(&sB[db][1][w * 512],        g + wOff + k0 + 32);
        async_copy16(&sB[db][1][w * 512 + 2048], g + wOff + 65536 + k0 + 32);
    };

    f32x4 acc[4][4];
#pragma unroll
    for (int i = 0; i < 4; ++i)
#pragma unroll
        for (int j = 0; j < 4; ++j)
            acc[i][j] = (f32x4){0.f, 0.f, 0.f, 0.f};

    if constexpr (PIPE) {
        // ---- double-buffered async pipeline: one __syncthreads per step ----
        stageAasync(0, 0);
        stageBasync(0, 0);
        __syncthreads();                       // drains prologue stage
        for (int tk = 0; tk < 16; ++tk) {
            const int cur = tk & 1, nb = cur ^ 1;
            if (tk + 1 < 16) {                 // issue next tile FIRST
                stageAasync((tk + 1) * 64, nb);
                stageBasync((tk + 1) * 64, nb);
            }
#pragma unroll
            for (int kk = 0; kk < 2; ++kk) {
                bf16x8 af[4], bw[4];
#pragma unroll
                for (int mi = 0; mi < 4; ++mi)
                    af[mi] = *(const bf16x8*)&sA[cur][kk][(wrow * 64 + mi * 16 + l16) * 32 + qs];
#pragma unroll
                for (int ni = 0; ni < 4; ++ni)
                    bw[ni] = *(const bf16x8*)&sB[cur][kk][(wcol * 64 + ni * 16 + l16) * 32 + qs];
#pragma unroll
                for (int mi = 0; mi < 4; ++mi)
#pragma unroll
                    for (int ni = 0; ni < 4; ++ni)
                        acc[mi][ni] = __builtin_amdgcn_mfma_f32_16x16x32_bf16(af[mi], bw[ni], acc[mi][ni], 0, 0, 0);
            }
            __syncthreads();                   // drain stage(t+1) (issued a full
        }                                      // compute ago) + publish/protect
    } else {
        // ---- r7 single-buffer path (control; used by the AF32/WF32 stages) ----
        for (int k0 = 0; k0 < 1024; k0 += 64) {
            bf16x8 va[4], vb[4];
            if (AF32) {
                const float* g = (const float*)Av;
                va[0] = cvt8(*(const f32x4*)(g + aOff + k0),              *(const f32x4*)(g + aOff + k0 + 4));
                va[1] = cvt8(*(const f32x4*)(g + aOff + 65536 + k0),      *(const f32x4*)(g + aOff + 65536 + k0 + 4));
                va[2] = cvt8(*(const f32x4*)(g + aOff + k0 + 32),         *(const f32x4*)(g + aOff + k0 + 36));
                va[3] = cvt8(*(const f32x4*)(g + aOff + 65536 + k0 + 32), *(const f32x4*)(g + aOff + 65536 + k0 + 36));
            }
            if (WF32) {
                const float* g = (const float*)Wp;
                vb[0] = cvt8(*(const f32x4*)(g + wOff + k0),              *(const f32x4*)(g + wOff + k0 + 4));
                vb[1] = cvt8(*(const f32x4*)(g + wOff + 65536 + k0),      *(const f32x4*)(g + wOff + 65536 + k0 + 4));
                vb[2] = cvt8(*(const f32x4*)(g + wOff + k0 + 32),         *(const f32x4*)(g + wOff + k0 + 36));
                vb[3] = cvt8(*(const f32x4*)(g + wOff + 65536 + k0 + 32), *(const f32x4*)(g + wOff + 65536 + k0 + 36));
            }
            __syncthreads();
            if (AF32) {
                *(bf16x8*)&sA[0][0][t * 8]        = va[0];
                *(bf16x8*)&sA[0][0][t * 8 + 2048] = va[1];
                *(bf16x8*)&sA[0][1][t * 8]        = va[2];
                *(bf16x8*)&sA[0][1][t * 8 + 2048] = va[3];
            } else {
                stageAasync(k0, 0);
            }
            if (WF32) {
                *(bf16x8*)&sB[0][0][t * 8]        = vb[0];
                *(bf16x8*)&sB[0][0][t * 8 + 2048] = vb[1];
                *(bf16x8*)&sB[0][1][t * 8]        = vb[2];
                *(bf16x8*)&sB[0][1][t * 8 + 2048] = vb[3];
            } else {
                stageBasync(k0, 0);
            }
            __syncthreads();

#pragma unroll
            for (int kk = 0; kk < 2; ++kk) {
                bf16x8 af[4], bw[4];
#pragma unroll
                for (int mi = 0; mi < 4; ++mi)
                    af[mi] = *(const bf16x8*)&sA[0][kk][(wrow * 64 + mi * 16 + l16) * 32 + qs];
#pragma unroll
                for (int ni = 0; ni < 4; ++ni)
                    bw[ni] = *(const bf16x8*)&sB[0][kk][(wcol * 64 + ni * 16 + l16) * 32 + qs];
#pragma unroll
                for (int mi = 0; mi < 4; ++mi)
#pragma unroll
                    for (int ni = 0; ni < 4; ++ni)
                        acc[mi][ni] = __builtin_amdgcn_mfma_f32_16x16x32_bf16(af[mi], bw[ni], acc[mi][ni], 0, 0, 0);
            }
        }
    }

    if (doRope) {
        const float bb = (float)(m0 >> 10);
        float s0, c0v, s1, c1v;
        sincosf(bb * expf((float)l16 * NEG_LN10K_32), &s0, &c0v);
        sincosf(bb * expf((float)(16 + l16) * NEG_LN10K_32), &s1, &c1v);
#pragma unroll
        for (int mi = 0; mi < 4; ++mi) {
#pragma unroll
            for (int r = 0; r < 4; ++r) {
                float x1 = acc[mi][0][r], x2 = acc[mi][2][r];
                acc[mi][0][r] = x1 * c0v - x2 * s0;
                acc[mi][2][r] = x2 * c0v + x1 * s0;
                x1 = acc[mi][1][r]; x2 = acc[mi][3][r];
                acc[mi][1][r] = x1 * c1v - x2 * s1;
                acc[mi][3][r] = x2 * c1v + x1 * s1;
            }
        }
    }

#pragma unroll
    for (int mi = 0; mi < 4; ++mi) {
#pragma unroll
        for (int ni = 0; ni < 4; ++ni) {
            const int col = n0 + wcol * 64 + ni * 16 + l16;
#pragma unroll
            for (int r = 0; r < 4; ++r) {
                const int row = m0 + wrow * 64 + mi * 16 + quad * 4 + r;
                float v = acc[mi][ni][r];
                if (R) v += R[(size_t)row * 1024 + col];
                C[(size_t)row * 1024 + col] = (bf16)v;
            }
        }
    }
}

// ---------------------------------------------------------------------------
// Flash attention (r2 known-good version, untouched). O written IN-PLACE over
// QP. No running max (|score| <~ 1.5), deferred denominator, wave-local P
// sync. sK0/sK1 bank-swizzled; sVt/sP stride-72 conflict-free.
// ---------------------------------------------------------------------------
__global__ __launch_bounds__(256) void attn_kernel(
    bf16* __restrict__ QP, const bf16* __restrict__ KP, const bf16* __restrict__ VP)
{
    const int fs   = blockIdx.y * 8 + blockIdx.x;
    const int xcd  = fs & 7;
    const int slot = fs >> 3;
    const int qt   = slot & 7;
    const int bh   = (xcd << 4) | (slot >> 3);
    const int tb = (bh >> 4) << 10;
    const int fb = (bh & 15) << 6;

    __shared__ __attribute__((aligned(16))) bf16 sK0[64 * 32];
    __shared__ __attribute__((aligned(16))) bf16 sK1[64 * 32];
    __shared__ __attribute__((aligned(16))) bf16 sVt[64 * 72];
    __shared__ __attribute__((aligned(16))) bf16 sP[4][32 * 72];

    const int t    = threadIdx.x;
    const int w    = t >> 6;
    const int lane = t & 63;
    const int l16  = lane & 15;
    const int quad = lane >> 4;

    const int sgr = ((t & 3) ^ ((t >> 3) & 3)) * 8;       // staging granule (swizzled)
    const int qs  = (quad ^ ((l16 >> 1) & 3)) * 8;        // frag-read slot

    bf16x8 qf[2][2];
#pragma unroll
    for (int mi = 0; mi < 2; ++mi)
#pragma unroll
        for (int kd = 0; kd < 2; ++kd)
            qf[mi][kd] = *(const bf16x8*)&QP[(size_t)(tb + qt * 128 + w * 32 + mi * 16 + l16) * 1024
                                            + fb + kd * 32 + quad * 8];

    f32x4 oacc[2][4];
#pragma unroll
    for (int i = 0; i < 2; ++i)
#pragma unroll
        for (int j = 0; j < 4; ++j)
            oacc[i][j] = (f32x4){0.f, 0.f, 0.f, 0.f};
    float psum[2][4];
#pragma unroll
    for (int i = 0; i < 2; ++i)
#pragma unroll
        for (int r = 0; r < 4; ++r) psum[i][r] = 0.f;

    for (int kt = 0; kt < 16; ++kt) {
        const bf16* kRow = KP + (size_t)(tb + kt * 64 + (t >> 2)) * 1024 + fb + sgr;
        const bf16x8 vk0 = *(const bf16x8*)(kRow);
        const bf16x8 vk1 = *(const bf16x8*)(kRow + 32);
        const bf16* vRow = VP + (size_t)(tb + kt * 64 + lane) * 1024 + fb;
        const bf16x8 vv0 = *(const bf16x8*)(vRow + w * 8);
        const bf16x8 vv1 = *(const bf16x8*)(vRow + (w + 4) * 8);

        __syncthreads();
        *(bf16x8*)&sK0[t * 8] = vk0;
        *(bf16x8*)&sK1[t * 8] = vk1;
#pragma unroll
        for (int j = 0; j < 8; ++j) sVt[(w * 8 + j) * 72 + lane]       = vv0[j];
#pragma unroll
        for (int j = 0; j < 8; ++j) sVt[((w + 4) * 8 + j) * 72 + lane] = vv1[j];
        __syncthreads();

        bf16x8 kf[4][2];
#pragma unroll
        for (int ni = 0; ni < 4; ++ni) {
            kf[ni][0] = *(const bf16x8*)&sK0[(ni * 16 + l16) * 32 + qs];
            kf[ni][1] = *(const bf16x8*)&sK1[(ni * 16 + l16) * 32 + qs];
        }
        f32x4 sfr[2][4];
#pragma unroll
        for (int mi = 0; mi < 2; ++mi)
#pragma unroll
            for (int ni = 0; ni < 4; ++ni) {
                f32x4 a = (f32x4){0.f, 0.f, 0.f, 0.f};
                a = __builtin_amdgcn_mfma_f32_16x16x32_bf16(qf[mi][0], kf[ni][0], a, 0, 0, 0);
                a = __builtin_amdgcn_mfma_f32_16x16x32_bf16(qf[mi][1], kf[ni][1], a, 0, 0, 0);
                sfr[mi][ni] = a * 0.125f;
            }

        // p = exp(s); accumulate per-lane denominator partials (no shuffles)
#pragma unroll
        for (int mi = 0; mi < 2; ++mi)
#pragma unroll
            for (int ni = 0; ni < 4; ++ni)
#pragma unroll
                for (int r = 0; r < 4; ++r) {
                    const float p = __expf(sfr[mi][ni][r]);
                    sfr[mi][ni][r] = p;
                    psum[mi][r] += p;
                }

        // P: C-layout -> A-operand layout via wave-private LDS strip
        bf16* sPw = &sP[w][0];
#pragma unroll
        for (int mi = 0; mi < 2; ++mi)
#pragma unroll
            for (int ni = 0; ni < 4; ++ni)
#pragma unroll
                for (int r = 0; r < 4; ++r)
                    sPw[(mi * 16 + quad * 4 + r) * 72 + ni * 16 + l16] = (bf16)sfr[mi][ni][r];
        asm volatile("s_waitcnt lgkmcnt(0)" ::: "memory");   // wave-local W->R order

#pragma unroll
        for (int kd = 0; kd < 2; ++kd) {
            bf16x8 pf[2], vf[4];
#pragma unroll
            for (int mi = 0; mi < 2; ++mi)
                pf[mi] = *(const bf16x8*)&sPw[(mi * 16 + l16) * 72 + kd * 32 + quad * 8];
#pragma unroll
            for (int di = 0; di < 4; ++di)
                vf[di] = *(const bf16x8*)&sVt[(di * 16 + l16) * 72 + kd * 32 + quad * 8];
#pragma unroll
            for (int mi = 0; mi < 2; ++mi)
#pragma unroll
                for (int di = 0; di < 4; ++di)
                    oacc[mi][di] = __builtin_amdgcn_mfma_f32_16x16x32_bf16(pf[mi], vf[di], oacc[mi][di], 0, 0, 0);
        }
    }

#pragma unroll
    for (int mi = 0; mi < 2; ++mi) {
#pragma unroll
        for (int r = 0; r < 4; ++r) {
            float l = psum[mi][r];
            l += __shfl_xor(l, 1);
            l += __shfl_xor(l, 2);
            l += __shfl_xor(l, 4);
            l += __shfl_xor(l, 8);
            const float inv = 1.f / l;
            const int row = tb + qt * 128 + w * 32 + mi * 16 + quad * 4 + r;
#pragma unroll
            for (int di = 0; di < 4; ++di) {
                const int col = fb + di * 16 + l16;
                QP[(size_t)row * 1024 + col] = (bf16)(oacc[mi][di][r] * inv);
            }
        }
    }
}

// ---------------------------------------------------------------------------
// LayerNorm: bf16 in, fp32 gamma/beta, fp32 out. One 128-thread block per row.
// ---------------------------------------------------------------------------
__global__ __launch_bounds__(128) void ln_kernel(const bf16* __restrict__ X,
                                                 const float* __restrict__ G,
                                                 const float* __restrict__ Bt,
                                                 float* __restrict__ Y)
{
    const int row = blockIdx.x;
    const int t   = threadIdx.x;
    const size_t base = (size_t)row * 1024 + t * 8;
    const bf16x8 xv = *(const bf16x8*)(X + base);
    float f[8];
    float s = 0.f, s2 = 0.f;
#pragma unroll
    for (int j = 0; j < 8; ++j) { f[j] = (float)xv[j]; s += f[j]; s2 += f[j] * f[j]; }
#pragma unroll
    for (int off = 1; off < 64; off <<= 1) { s += __shfl_xor(s, off); s2 += __shfl_xor(s2, off); }
    __shared__ float ss[2], ssq[2];
    if ((t & 63) == 0) { ss[t >> 6] = s; ssq[t >> 6] = s2; }
    __syncthreads();
    s  = ss[0] + ss[1];
    s2 = ssq[0] + ssq[1];
    const float mu  = s * (1.f / 1024.f);
    const float inv = rsqrtf(s2 * (1.f / 1024.f) - mu * mu + 1e-5f);
    const f32x4 g0 = *(const f32x4*)(G + t * 8);
    const f32x4 g1 = *(const f32x4*)(G + t * 8 + 4);
    const f32x4 b0 = *(const f32x4*)(Bt + t * 8);
    const f32x4 b1 = *(const f32x4*)(Bt + t * 8 + 4);
    f32x4 y0, y1;
#pragma unroll
    for (int j = 0; j < 4; ++j) {
        y0[j] = (f[j]     - mu) * inv * g0[j] + b0[j];
        y1[j] = (f[j + 4] - mu) * inv * g1[j] + b1[j];
    }
    *(f32x4*)(Y + base)     = y0;
    *(f32x4*)(Y + base + 4) = y1;
}

// ---------------------------------------------------------------------------
extern "C" void kernel_launch(void* const* d_in, const int* in_sizes, int n_in,
                              void* d_out, int out_size, void* d_ws, size_t ws_size,
                              hipStream_t stream)
{
    const float* query = (const float*)d_in[0];
    const float* key   = (const float*)d_in[1];
    const float* value = (const float*)d_in[2];
    const float* Wq    = (const float*)d_in[3];
    const float* Wk    = (const float*)d_in[4];
    const float* Wv    = (const float*)d_in[5];
    const float* ipw   = (const float*)d_in[6];
    const float* opw   = (const float*)d_in[7];
    const float* pw    = (const float*)d_in[8];
    const float* gamma = (const float*)d_in[9];
    const float* beta  = (const float*)d_in[10];

    const size_t ACT = (size_t)8192 * 1024;   // act slot: 8.39M elems (16.78 MB)
    const size_t MW  = 1048576;               // weight matrix: 1M elems (2 MB)
    bf16* o0 = (bf16*)d_out;                  // d_out fp32 = 2 bf16 act slots
    bf16* o1 = o0 + ACT;

    dim3 blk(256);
    dim3 g3(8, 64, 3);
    dim3 g1(8, 64, 1);
    dim3 ga(8, 128);

    // Full tier needs 6 weight mats + 2 act slots = 45.6 MB (round 4 proved >=50.3)
    const bool full = ws_size >= (6 * MW + 2 * ACT) * sizeof(bf16);

    if (full) {
        bf16* wq  = (bf16*)d_ws;        // persistent bf16 weights
        bf16* wk  = wq + MW;
        bf16* wqa = wq + 2 * MW;
        bf16* wka = wq + 3 * MW;
        bf16* Fv  = wq + 4 * MW;        // fused Wva@Wv
        bf16* Fo  = wq + 5 * MW;        // fused pw@opw
        bf16* sltA = wq + 6 * MW;       // act slot A
        bf16* sltB = sltA + ACT;        // act slot B
        // transients (dead before slots hold activations)
        bf16* tWva = sltA;              // A-operands for precompute
        bf16* tpw  = sltA + MW;
        bf16* WvT  = sltB;              // transposed B-operands
        bf16* opwT = sltB + MW;

        // 0) weight converts + transposes
        wconv6<<<dim3(512, 1, 6), blk, 0, stream>>>(
            Wq, Wk, ipw, ipw + MW, ipw + 2 * MW, pw,
            wq, wk, wqa, wka, tWva, tpw);
        prepT<<<dim3(16, 16, 2), blk, 0, stream>>>(Wv, opw, WvT, opwT);
        // 1) precompute fused weights: Fv = Wva@Wv, Fo = pw@opw  (PIPE dbuf)
        gemm_bt<0, 0, 1><<<dim3(8, 8, 2), blk, 0, stream>>>(
            tWva, tpw, tpw, WvT, opwT, opwT, Fv, Fo, Fo, nullptr, 0);
        // 2) q(rope)=sltA, k(rope)=sltB, vp = value@Fv^T = o0 (r7 control path)
        gemm_bt<1, 0, 0><<<g3, blk, 0, stream>>>(query, key, value, wq, wk, Fv,
                                                 sltA, sltB, o0, nullptr, 0b011);
        // 3) qp = q @ Wqa^T   (sltA -> o1)  (PIPE dbuf)
        gemm_bt<0, 0, 1><<<g1, blk, 0, stream>>>(sltA, sltA, sltA, wqa, wqa, wqa,
                                                 o1, o1, o1, nullptr, 0);
        // 4) kp = k @ Wka^T   (sltB -> sltA)  (PIPE dbuf)
        gemm_bt<0, 0, 1><<<g1, blk, 0, stream>>>(sltB, sltB, sltB, wka, wka, wka,
                                                 sltA, sltA, sltA, nullptr, 0);
        // 5) attention: qp=o1 (O in-place), kp=sltA, vp=o0
        attn_kernel<<<ga, blk, 0, stream>>>(o1, sltA, o0);
        // 6) x = o @ Fo^T + query (o1 -> sltB)  (PIPE dbuf)
        gemm_bt<0, 0, 1><<<g1, blk, 0, stream>>>(o1, o1, o1, Fo, Fo, Fo,
                                                 sltB, sltB, sltB, query, 0);
        // 7) LayerNorm -> d_out fp32
        ln_kernel<<<8192, 128, 0, stream>>>(sltB, gamma, beta, (float*)d_out);
    } else {
        // 33.5 MB fallback: round-3 schedule, fp32 weights, attn in-place
        bf16* b0 = (bf16*)d_ws;
        bf16* b1 = b0 + ACT;
        gemm_bt<1, 1, 0><<<g3, blk, 0, stream>>>(query, key, value, Wq, Wk, Wv,
                                                 b0, b1, o0, nullptr, 0b011);
        gemm_bt<0, 1, 0><<<g1, blk, 0, stream>>>(o0, o0, o0, ipw + 2 * MW, ipw, ipw,
                                                 o1, o1, o1, nullptr, 0);
        gemm_bt<0, 1, 0><<<g1, blk, 0, stream>>>(b0, b0, b0, ipw, ipw, ipw,
                                                 o0, o0, o0, nullptr, 0);
        gemm_bt<0, 1, 0><<<g1, blk, 0, stream>>>(b1, b1, b1, ipw + MW, ipw, ipw,
                                                 b0, b0, b0, nullptr, 0);
        attn_kernel<<<ga, blk, 0, stream>>>(o0, b0, o1);   // o -> o0 in-place
        gemm_bt<0, 1, 0><<<g1, blk, 0, stream>>>(o0, o0, o0, opw, opw, opw,
                                                 b0, b0, b0, nullptr, 0);
        gemm_bt<0, 1, 0><<<g1, blk, 0, stream>>>(b0, b0, b0, pw, pw, pw,
                                                 b1, b1, b1, query, 0);
        ln_kernel<<<8192, 128, 0, stream>>>(b1, gamma, beta, (float*)d_out);
    }
}